// Round 8
// baseline (257.577 us; speedup 1.0000x reference)
//
#include <hip/hip_runtime.h>

typedef __bf16 bf16x8 __attribute__((ext_vector_type(8)));
typedef float  f32x4  __attribute__((ext_vector_type(4)));

union U8 { uint4 v; unsigned short u[8]; };

static __device__ __forceinline__ float bf2f(unsigned short u) {
    union { unsigned int i; float f; } c; c.i = ((unsigned int)u) << 16; return c.f;
}
static __device__ __forceinline__ unsigned short f2bf(float f) {
    union { float f; unsigned int i; } c; c.f = f;
    unsigned int x = c.i;
    unsigned int r = (x + 0x7FFFu + ((x >> 16) & 1u)) >> 16;  // RNE
    return (unsigned short)r;
}

static __device__ __forceinline__ U8 load8(const float* p) {
    U8 r;
    const float4 a = *(const float4*)p;
    const float4 b = *(const float4*)(p + 4);
    r.u[0] = f2bf(a.x); r.u[1] = f2bf(a.y); r.u[2] = f2bf(a.z); r.u[3] = f2bf(a.w);
    r.u[4] = f2bf(b.x); r.u[5] = f2bf(b.y); r.u[6] = f2bf(b.z); r.u[7] = f2bf(b.w);
    return r;
}

// async global->LDS, 16B per lane. LDS dest must be wave-uniform base (+lane*16 by HW).
static __device__ __forceinline__ void gld_lds16(const void* g, void* l) {
    __builtin_amdgcn_global_load_lds(
        (const __attribute__((address_space(1))) unsigned int*)g,
        (__attribute__((address_space(3))) unsigned int*)l, 16, 0, 0);
}

// ---- merged pack pass: bid<2048: x f32->bf16 + bias concat; else weight transpose ----
// wAllT[640][512] = [wq^T | wk^T | wv^T], woT[512][512], ball[640] = [bq|bk|bv]
__global__ __launch_bounds__(256)
void pack(const float* __restrict__ x, unsigned short* __restrict__ xb,
          const float* __restrict__ bq, const float* __restrict__ bk,
          const float* __restrict__ bv, float* __restrict__ ball,
          const float* __restrict__ wv, const float* __restrict__ wo,
          const float* __restrict__ wq, const float* __restrict__ wk,
          unsigned short* __restrict__ wAllT, unsigned short* __restrict__ woT)
{
    const int bid = blockIdx.x, t = threadIdx.x;
    if (bid < 2048) {
        const long i = ((long)bid * 256 + t) * 16;
        U8 a = load8(x + i);
        U8 b = load8(x + i + 8);
        *(uint4*)(xb + i) = a.v;
        *(uint4*)(xb + i + 8) = b.v;
        if (bid == 0) {
            ball[t]       = t < 64 ? bq[t] : (t < 128 ? bk[t - 64] : bv[t - 128]);
            ball[t + 256] = bv[t + 128];
            if (t < 128) ball[t + 512] = bv[t + 384];
        }
        return;
    }
    // transpose+convert: dst[C][R] = src[R][C]^T, 64x64 tiles
    __shared__ float sT[64][65];
    const int b2 = bid - 2048;
    const int zz = b2 >> 6, rem = b2 & 63;
    const int cx = rem & 7, ry = rem >> 3;
    const float* src; unsigned short* dst; int C;
    if      (zz == 0) { src = wv; dst = wAllT + 128 * 512; C = 512; }
    else if (zz == 1) { src = wo; dst = woT;               C = 512; }
    else if (zz == 2) { src = wq; dst = wAllT;             C = 64;  }
    else              { src = wk; dst = wAllT + 64 * 512;  C = 64;  }
    const int R = 512;
    const int c0 = cx * 64, r0 = ry * 64;
    if (c0 >= C) return;
    #pragma unroll
    for (int k = 0; k < 16; ++k) {
        const int lin = k * 256 + t;
        const int i = lin >> 6, j = lin & 63;
        sT[i][j] = src[(long)(r0 + i) * C + c0 + j];
    }
    __syncthreads();
    #pragma unroll
    for (int k = 0; k < 16; ++k) {
        const int lin = k * 256 + t;
        const int o = lin >> 6, i2 = lin & 63;
        dst[(long)(c0 + o) * R + r0 + i2] = f2bf(sT[i2][o]);
    }
}

// ---- 64x128-tile GEMM, BK=64, dbuf 1-barrier + XCD swizzle (byte-identical r6/r7) ----
template<bool BIAS, bool RES, bool OUT_F32, bool MIXED, int NCOL>
__global__ __launch_bounds__(256, 3)
void gemm64(const unsigned short* __restrict__ A, int lda,
            const unsigned short* __restrict__ B, int ldb,
            void* __restrict__ Cp, int ldc,
            void* __restrict__ Cp2,
            const float* __restrict__ bias,
            const float* __restrict__ resid,
            int K)
{
    __shared__ __align__(16) unsigned short sMem[2][12288];  // 2 x 24 KB (sA 8K | sB 16K)

    const int t = threadIdx.x, wave = t >> 6, lane = t & 63;
    const int lr = lane & 15, quad = lane >> 4;

    const int bid = blockIdx.x;
    const int sw  = (bid & 7) * (NCOL * 32) + (bid >> 3);
    const int rowBase = (sw / NCOL) * 64;
    const int colBase = (sw % NCOL) * 128;
    const int wm = (wave & 1) * 32, wn = (wave >> 1) * 64;

    const int srow  = lane >> 3;
    const int sslot = lane & 7;
    const int swz   = (sslot ^ srow) << 4;

    f32x4 acc[2][4];
    #pragma unroll
    for (int mt = 0; mt < 2; ++mt)
        #pragma unroll
        for (int nt = 0; nt < 4; ++nt) acc[mt][nt] = (f32x4){0.f, 0.f, 0.f, 0.f};

    auto STAGE = [&](int buf, int kt) {
        unsigned short* sA = sMem[buf];
        unsigned short* sB = sMem[buf] + 4096;
        #pragma unroll
        for (int is = 0; is < 2; ++is) {
            const int r0 = wave * 16 + is * 8;
            gld_lds16((const char*)A + ((long)(rowBase + r0 + srow) * lda + kt) * 2 + swz,
                      (char*)sA + r0 * 128);
        }
        #pragma unroll
        for (int is = 0; is < 4; ++is) {
            const int r0 = wave * 32 + is * 8;
            gld_lds16((const char*)B + ((long)(colBase + r0 + srow) * ldb + kt) * 2 + swz,
                      (char*)sB + r0 * 128);
        }
    };

    STAGE(0, 0);
    __syncthreads();

    int cur = 0;
    for (int kt = 0; kt < K; kt += 64) {
        if (kt + 64 < K) STAGE(cur ^ 1, kt + 64);

        const unsigned short* sA = sMem[cur];
        const unsigned short* sB = sMem[cur] + 4096;
        #pragma unroll
        for (int ks = 0; ks < 2; ++ks) {
            const int kb = ks * 64 + quad * 16;
            bf16x8 bfr[4];
            #pragma unroll
            for (int nt = 0; nt < 4; ++nt) {
                const int row = wn + nt * 16 + lr;
                bfr[nt] = *(const bf16x8*)((const char*)sB + row * 128 + (kb ^ ((row & 7) << 4)));
            }
            #pragma unroll
            for (int mt = 0; mt < 2; ++mt) {
                const int row = wm + mt * 16 + lr;
                bf16x8 af = *(const bf16x8*)((const char*)sA + row * 128 + (kb ^ ((row & 7) << 4)));
                #pragma unroll
                for (int nt = 0; nt < 4; ++nt)
                    acc[mt][nt] = __builtin_amdgcn_mfma_f32_16x16x32_bf16(af, bfr[nt], acc[mt][nt], 0, 0, 0);
            }
        }
        __syncthreads();
        cur ^= 1;
    }

    if (MIXED && colBase >= 128) {
        unsigned short* sT = sMem[0];
        #pragma unroll
        for (int mt = 0; mt < 2; ++mt)
            #pragma unroll
            for (int nt = 0; nt < 4; ++nt) {
                const int row0 = wm + mt * 16 + quad * 4;
                const int col  = wn + nt * 16 + lr;
                const float b = BIAS ? bias[colBase + col] : 0.f;
                ushort4 v4;
                v4.x = f2bf(acc[mt][nt][0] + b);
                v4.y = f2bf(acc[mt][nt][1] + b);
                v4.z = f2bf(acc[mt][nt][2] + b);
                v4.w = f2bf(acc[mt][nt][3] + b);
                *(ushort4*)&sT[col * 72 + row0] = v4;
            }
        __syncthreads();
        unsigned short* C2 = (unsigned short*)Cp2;
        const int bat = rowBase >> 11, key0 = rowBase & 2047;
        const long vcol0 = colBase - 128;
        #pragma unroll
        for (int ro = 0; ro < 4; ++ro) {
            const int flat = ro * 256 + t;
            const int col = flat >> 3, ch = flat & 7;
            const uint4 v = *(const uint4*)&sT[col * 72 + ch * 8];
            *(uint4*)&C2[((long)bat * 512 + vcol0 + col) * 2048 + key0 + ch * 8] = v;
        }
        return;
    }

    float* Cf = (float*)Cp;
    unsigned short* Cb = (unsigned short*)Cp;
    #pragma unroll
    for (int mt = 0; mt < 2; ++mt)
        #pragma unroll
        for (int nt = 0; nt < 4; ++nt) {
            const int row0 = rowBase + wm + mt * 16 + quad * 4;
            const int col  = colBase + wn + nt * 16 + lr;
            const float b = BIAS ? bias[col] : 0.f;
            #pragma unroll
            for (int r = 0; r < 4; ++r) {
                const int row = row0 + r;
                float v = acc[mt][nt][r] + b;
                if (RES)     v += resid[(long)row * ldc + col];
                if (OUT_F32) Cf[(long)row * ldc + col] = v;
                else         Cb[(long)row * ldc + col] = f2bf(v);
            }
        }
}

// Fused attention, 8-wave blocks (r7 schedule) with two LDS cuts:
// (1) NO sK staging — K fragments read DIRECTLY from global. With z=bid&7 XCD
//     affinity, each XCD serves one batch: K (0.5 MB) + V (2 MB) are L2-resident
//     (4 MB/XCD). Removes all sK LDS reads/writes and the gld_lds/vmcnt barrier
//     coupling. Waves 4-7 are now pure PV waves (V prefetch + PV).
// (2) Conflict-free sP writes: column swizzle col ^= ((row>>2)&3)<<4 within the
//     64-col row (write XOR = quad<<4; read XOR = (lr>>2)<<4). Bank check per
//     write instr: quad*16 + (nt^quad)*8 + 4r -> all quads distinct for every
//     (nt,r); lr/2 gives 2 lanes/bank (free).
__global__ __launch_bounds__(512, 4)
void flash_attn(const unsigned short* __restrict__ QK,  // [8*2048][128] (Q|K)
                const unsigned short* __restrict__ VT,  // [8][512][2048]
                unsigned short* __restrict__ O)         // [8*2048][512]
{
    __shared__ __align__(16) unsigned short sP[2][64 * 72];   // 2 x 9 KB
    __shared__ float sL[64];

    const int bid = blockIdx.x;
    const int z  = bid & 7;          // batch -> XCD (round-robin dispatch)
    const int rr = bid >> 3;
    const int cs = rr & 1;           // 256-col split
    const int qt = rr >> 1;          // Q tile (64 rows), 32 tiles

    const int t = threadIdx.x, wave = t >> 6, lane = t & 63;
    const int lr = lane & 15, quad = lane >> 4;
    const int sw = wave & 3;         // role index within the 4-wave group
    const bool isS = wave < 4;       // wave-uniform

    const long qrow0 = (long)z * 2048 + qt * 64;
    bf16x8 qa0, qa1;
    if (isS) {
        const unsigned short* qp = QK + (qrow0 + sw * 16 + lr) * 128 + quad * 8;
        qa0 = *(const bf16x8*)(qp);
        qa1 = *(const bf16x8*)(qp + 32);
    }

    // K rows at QK[z*2048+key][64..127]: 256 B row stride, +128 B col offset
    const char* Kb = (const char*)(QK + (long)z * 2048 * 128 + 64);
    const unsigned short* Vb = VT + (long)z * 512 * 2048
                                  + ((long)cs * 256 + wave * 32) * 2048;

    const int wsw = quad << 4;       // write-side col XOR ((row>>2)&3 == quad)
    const int rsw = (lr >> 2) << 4;  // read-side col XOR ((row>>2)&3 == lr>>2)

    f32x4 acc[4][2];   // [mt][nt]: rows mt*16+quad*4+r, cols cs*256+wave*32+nt*16+lr
    #pragma unroll
    for (int mt = 0; mt < 4; ++mt)
        #pragma unroll
        for (int nt = 0; nt < 2; ++nt) acc[mt][nt] = (f32x4){0.f, 0.f, 0.f, 0.f};
    float lsum[4] = {0.f, 0.f, 0.f, 0.f};

    int cur = 0;
    for (int kt = 0; kt < 32; ++kt) {
        const int key0 = kt * 64;

        // prefetch V frags for THIS tile (L2-resident; latency hides under S-phase
        // for S-waves, under barrier wait for PV-waves)
        bf16x8 vv[2][2];
        #pragma unroll
        for (int nt = 0; nt < 2; ++nt) {
            const unsigned short* vp = Vb + (long)(nt * 16 + lr) * 2048 + key0 + quad * 8;
            vv[nt][0] = *(const bf16x8*)(vp);
            vv[nt][1] = *(const bf16x8*)(vp + 32);
        }

        if (isS) {
            // S = Q K^T for rows sw*16..+15 x all 64 keys; K frags direct from L2
            __bf16* sPb = (__bf16*)sP[cur];
            #pragma unroll
            for (int nt = 0; nt < 4; ++nt) {
                const char* kp = Kb + (long)(key0 + nt * 16 + lr) * 256 + quad * 16;
                bf16x8 k0 = *(const bf16x8*)(kp);
                bf16x8 k1 = *(const bf16x8*)(kp + 64);
                f32x4 sv = (f32x4){0.f, 0.f, 0.f, 0.f};
                sv = __builtin_amdgcn_mfma_f32_16x16x32_bf16(qa0, k0, sv, 0, 0, 0);
                sv = __builtin_amdgcn_mfma_f32_16x16x32_bf16(qa1, k1, sv, 0, 0, 0);
                #pragma unroll
                for (int r = 0; r < 4; ++r) {
                    const float e = __expf(sv[r]);
                    const __bf16 pb = (__bf16)e;       // v_cvt RNE
                    lsum[r] += (float)pb;
                    sPb[(sw * 16 + quad * 4 + r) * 72 + ((nt * 16 + lr) ^ wsw)] = pb;
                }
            }
        }

        __syncthreads();   // publishes sP[cur]

        // O += P V  (all 8 waves; A-frags of P from LDS, B-frags prefetched)
        const unsigned short* sPc = sP[cur];
        __builtin_amdgcn_s_setprio(1);
        #pragma unroll
        for (int mt = 0; mt < 4; ++mt) {
            const int rbase = (mt * 16 + lr) * 72;
            bf16x8 p0 = *(const bf16x8*)&sPc[rbase + ((quad * 8) ^ rsw)];
            bf16x8 p1 = *(const bf16x8*)&sPc[rbase + ((quad * 8 + 32) ^ rsw)];
            acc[mt][0] = __builtin_amdgcn_mfma_f32_16x16x32_bf16(p0, vv[0][0], acc[mt][0], 0, 0, 0);
            acc[mt][0] = __builtin_amdgcn_mfma_f32_16x16x32_bf16(p1, vv[0][1], acc[mt][0], 0, 0, 0);
            acc[mt][1] = __builtin_amdgcn_mfma_f32_16x16x32_bf16(p0, vv[1][0], acc[mt][1], 0, 0, 0);
            acc[mt][1] = __builtin_amdgcn_mfma_f32_16x16x32_bf16(p1, vv[1][1], acc[mt][1], 0, 0, 0);
        }
        __builtin_amdgcn_s_setprio(0);
        cur ^= 1;
    }

    // row sums (S-waves) -> sL -> all waves, then O = acc / l
    if (isS) {
        #pragma unroll
        for (int r = 0; r < 4; ++r) {
            float v = lsum[r];
            v += __shfl_xor(v, 1); v += __shfl_xor(v, 2);
            v += __shfl_xor(v, 4); v += __shfl_xor(v, 8);
            lsum[r] = v;
        }
        if (lr == 0) {
            #pragma unroll
            for (int r = 0; r < 4; ++r) sL[sw * 16 + quad * 4 + r] = lsum[r];
        }
    }
    __syncthreads();

    #pragma unroll
    for (int mt = 0; mt < 4; ++mt) {
        float inv[4];
        #pragma unroll
        for (int r = 0; r < 4; ++r) inv[r] = 1.0f / sL[mt * 16 + quad * 4 + r];
        #pragma unroll
        for (int nt = 0; nt < 2; ++nt) {
            const int col = cs * 256 + wave * 32 + nt * 16 + lr;
            #pragma unroll
            for (int r = 0; r < 4; ++r) {
                const long row = qrow0 + mt * 16 + quad * 4 + r;
                O[row * 512 + col] = f2bf(acc[mt][nt][r] * inv[r]);
            }
        }
    }
}

extern "C" void kernel_launch(void* const* d_in, const int* in_sizes, int n_in,
                              void* d_out, int out_size, void* d_ws, size_t ws_size,
                              hipStream_t stream)
{
    const float* x  = (const float*)d_in[0];
    const float* wq = (const float*)d_in[1];
    const float* bq = (const float*)d_in[2];
    const float* wk = (const float*)d_in[3];
    const float* bk = (const float*)d_in[4];
    const float* wv = (const float*)d_in[5];
    const float* bv = (const float*)d_in[6];
    const float* wo = (const float*)d_in[7];
    const float* bo = (const float*)d_in[8];

    const int W = 512;
    float* out = (float*)d_out;
    dim3 blk(256);
    char* ws = (char*)d_ws;

    const size_t NEED = 56ull << 20;
    if (ws_size < NEED) return;  // zero-output signature

    unsigned short* QK    = (unsigned short*)(ws);                  //  4 MB [16384 x 128] (Q|K)
    unsigned short* VT    = (unsigned short*)(ws + ( 4ull << 20));  // 16 MB [8][512][2048]
    unsigned short* O     = (unsigned short*)(ws + (20ull << 20));  // 16 MB [16384 x 512]
    unsigned short* xb    = (unsigned short*)(ws + (36ull << 20));  // 16 MB [16384 x 512]
    unsigned short* wAllT = (unsigned short*)(ws + (52ull << 20));  // 640 KB [640][512]
    unsigned short* woT   = (unsigned short*)(ws + (53ull << 20));  // 512 KB [512][512]
    float*          ball  = (float*)         (ws + (53ull << 20) + (512ull << 10)); // 2.5 KB

    // pack: x->bf16, bias concat, weights -> bf16 B^T layouts (merged launch)
    pack<<<dim3(2048 + 256), blk, 0, stream>>>(x, xb, bq, bk, bv, ball,
                                               wv, wo, wq, wk, wAllT, woT);

    // Fused QKV projection: [QK | V] = xb @ [wq|wk|wv] + [bq|bk|bv]
    gemm64<true, false, false, true, 5><<<dim3(1280), blk, 0, stream>>>(
        xb, W, wAllT, W, QK, 128, VT, ball, nullptr, W);

    // Fused attention (no S): O = softmax(Q K^T) V — 8-wave blocks, 512 blocks
    flash_attn<<<dim3(512), dim3(512), 0, stream>>>(QK, VT, O);

    // out = O @ wo + bo + x  (fp32)
    gemm64<true, true, true, false, 4><<<dim3(1024), blk, 0, stream>>>(
        O, W, woT, W, out, W, nullptr, bo, x, W);
}

// Round 9
// 222.218 us; speedup vs baseline: 1.1591x; 1.1591x over previous
//
#include <hip/hip_runtime.h>

typedef __bf16 bf16x8 __attribute__((ext_vector_type(8)));
typedef float  f32x4  __attribute__((ext_vector_type(4)));

union U8 { uint4 v; unsigned short u[8]; };

static __device__ __forceinline__ float bf2f(unsigned short u) {
    union { unsigned int i; float f; } c; c.i = ((unsigned int)u) << 16; return c.f;
}
static __device__ __forceinline__ unsigned short f2bf(float f) {
    union { float f; unsigned int i; } c; c.f = f;
    unsigned int x = c.i;
    unsigned int r = (x + 0x7FFFu + ((x >> 16) & 1u)) >> 16;  // RNE
    return (unsigned short)r;
}

static __device__ __forceinline__ U8 load8(const float* p) {
    U8 r;
    const float4 a = *(const float4*)p;
    const float4 b = *(const float4*)(p + 4);
    r.u[0] = f2bf(a.x); r.u[1] = f2bf(a.y); r.u[2] = f2bf(a.z); r.u[3] = f2bf(a.w);
    r.u[4] = f2bf(b.x); r.u[5] = f2bf(b.y); r.u[6] = f2bf(b.z); r.u[7] = f2bf(b.w);
    return r;
}

// async global->LDS, 16B per lane. LDS dest must be wave-uniform base (+lane*16 by HW).
static __device__ __forceinline__ void gld_lds16(const void* g, void* l) {
    __builtin_amdgcn_global_load_lds(
        (const __attribute__((address_space(1))) unsigned int*)g,
        (__attribute__((address_space(3))) unsigned int*)l, 16, 0, 0);
}

// ---- merged pack pass: bid<2048: x f32->bf16 + bias concat; else weight transpose ----
// wAllT[640][512] = [wq^T | wk^T | wv^T], woT[512][512], ball[640] = [bq|bk|bv]
__global__ __launch_bounds__(256)
void pack(const float* __restrict__ x, unsigned short* __restrict__ xb,
          const float* __restrict__ bq, const float* __restrict__ bk,
          const float* __restrict__ bv, float* __restrict__ ball,
          const float* __restrict__ wv, const float* __restrict__ wo,
          const float* __restrict__ wq, const float* __restrict__ wk,
          unsigned short* __restrict__ wAllT, unsigned short* __restrict__ woT)
{
    const int bid = blockIdx.x, t = threadIdx.x;
    if (bid < 2048) {
        const long i = ((long)bid * 256 + t) * 16;
        U8 a = load8(x + i);
        U8 b = load8(x + i + 8);
        *(uint4*)(xb + i) = a.v;
        *(uint4*)(xb + i + 8) = b.v;
        if (bid == 0) {
            ball[t]       = t < 64 ? bq[t] : (t < 128 ? bk[t - 64] : bv[t - 128]);
            ball[t + 256] = bv[t + 128];
            if (t < 128) ball[t + 512] = bv[t + 384];
        }
        return;
    }
    // transpose+convert: dst[C][R] = src[R][C]^T, 64x64 tiles
    __shared__ float sT[64][65];
    const int b2 = bid - 2048;
    const int zz = b2 >> 6, rem = b2 & 63;
    const int cx = rem & 7, ry = rem >> 3;
    const float* src; unsigned short* dst; int C;
    if      (zz == 0) { src = wv; dst = wAllT + 128 * 512; C = 512; }
    else if (zz == 1) { src = wo; dst = woT;               C = 512; }
    else if (zz == 2) { src = wq; dst = wAllT;             C = 64;  }
    else              { src = wk; dst = wAllT + 64 * 512;  C = 64;  }
    const int R = 512;
    const int c0 = cx * 64, r0 = ry * 64;
    if (c0 >= C) return;
    #pragma unroll
    for (int k = 0; k < 16; ++k) {
        const int lin = k * 256 + t;
        const int i = lin >> 6, j = lin & 63;
        sT[i][j] = src[(long)(r0 + i) * C + c0 + j];
    }
    __syncthreads();
    #pragma unroll
    for (int k = 0; k < 16; ++k) {
        const int lin = k * 256 + t;
        const int o = lin >> 6, i2 = lin & 63;
        dst[(long)(c0 + o) * R + r0 + i2] = f2bf(sT[i2][o]);
    }
}

// ---- 64x128-tile GEMM, BK=64, dbuf 1-barrier + XCD swizzle (byte-identical r6/r7) ----
template<bool BIAS, bool RES, bool OUT_F32, bool MIXED, int NCOL>
__global__ __launch_bounds__(256, 3)
void gemm64(const unsigned short* __restrict__ A, int lda,
            const unsigned short* __restrict__ B, int ldb,
            void* __restrict__ Cp, int ldc,
            void* __restrict__ Cp2,
            const float* __restrict__ bias,
            const float* __restrict__ resid,
            int K)
{
    __shared__ __align__(16) unsigned short sMem[2][12288];  // 2 x 24 KB (sA 8K | sB 16K)

    const int t = threadIdx.x, wave = t >> 6, lane = t & 63;
    const int lr = lane & 15, quad = lane >> 4;

    const int bid = blockIdx.x;
    const int sw  = (bid & 7) * (NCOL * 32) + (bid >> 3);
    const int rowBase = (sw / NCOL) * 64;
    const int colBase = (sw % NCOL) * 128;
    const int wm = (wave & 1) * 32, wn = (wave >> 1) * 64;

    const int srow  = lane >> 3;
    const int sslot = lane & 7;
    const int swz   = (sslot ^ srow) << 4;

    f32x4 acc[2][4];
    #pragma unroll
    for (int mt = 0; mt < 2; ++mt)
        #pragma unroll
        for (int nt = 0; nt < 4; ++nt) acc[mt][nt] = (f32x4){0.f, 0.f, 0.f, 0.f};

    auto STAGE = [&](int buf, int kt) {
        unsigned short* sA = sMem[buf];
        unsigned short* sB = sMem[buf] + 4096;
        #pragma unroll
        for (int is = 0; is < 2; ++is) {
            const int r0 = wave * 16 + is * 8;
            gld_lds16((const char*)A + ((long)(rowBase + r0 + srow) * lda + kt) * 2 + swz,
                      (char*)sA + r0 * 128);
        }
        #pragma unroll
        for (int is = 0; is < 4; ++is) {
            const int r0 = wave * 32 + is * 8;
            gld_lds16((const char*)B + ((long)(colBase + r0 + srow) * ldb + kt) * 2 + swz,
                      (char*)sB + r0 * 128);
        }
    };

    STAGE(0, 0);
    __syncthreads();

    int cur = 0;
    for (int kt = 0; kt < K; kt += 64) {
        if (kt + 64 < K) STAGE(cur ^ 1, kt + 64);

        const unsigned short* sA = sMem[cur];
        const unsigned short* sB = sMem[cur] + 4096;
        #pragma unroll
        for (int ks = 0; ks < 2; ++ks) {
            const int kb = ks * 64 + quad * 16;
            bf16x8 bfr[4];
            #pragma unroll
            for (int nt = 0; nt < 4; ++nt) {
                const int row = wn + nt * 16 + lr;
                bfr[nt] = *(const bf16x8*)((const char*)sB + row * 128 + (kb ^ ((row & 7) << 4)));
            }
            #pragma unroll
            for (int mt = 0; mt < 2; ++mt) {
                const int row = wm + mt * 16 + lr;
                bf16x8 af = *(const bf16x8*)((const char*)sA + row * 128 + (kb ^ ((row & 7) << 4)));
                #pragma unroll
                for (int nt = 0; nt < 4; ++nt)
                    acc[mt][nt] = __builtin_amdgcn_mfma_f32_16x16x32_bf16(af, bfr[nt], acc[mt][nt], 0, 0, 0);
            }
        }
        __syncthreads();
        cur ^= 1;
    }

    if (MIXED && colBase >= 128) {
        unsigned short* sT = sMem[0];
        #pragma unroll
        for (int mt = 0; mt < 2; ++mt)
            #pragma unroll
            for (int nt = 0; nt < 4; ++nt) {
                const int row0 = wm + mt * 16 + quad * 4;
                const int col  = wn + nt * 16 + lr;
                const float b = BIAS ? bias[colBase + col] : 0.f;
                ushort4 v4;
                v4.x = f2bf(acc[mt][nt][0] + b);
                v4.y = f2bf(acc[mt][nt][1] + b);
                v4.z = f2bf(acc[mt][nt][2] + b);
                v4.w = f2bf(acc[mt][nt][3] + b);
                *(ushort4*)&sT[col * 72 + row0] = v4;
            }
        __syncthreads();
        unsigned short* C2 = (unsigned short*)Cp2;
        const int bat = rowBase >> 11, key0 = rowBase & 2047;
        const long vcol0 = colBase - 128;
        #pragma unroll
        for (int ro = 0; ro < 4; ++ro) {
            const int flat = ro * 256 + t;
            const int col = flat >> 3, ch = flat & 7;
            const uint4 v = *(const uint4*)&sT[col * 72 + ch * 8];
            *(uint4*)&C2[((long)bat * 512 + vcol0 + col) * 2048 + key0 + ch * 8] = v;
        }
        return;
    }

    float* Cf = (float*)Cp;
    unsigned short* Cb = (unsigned short*)Cp;
    #pragma unroll
    for (int mt = 0; mt < 2; ++mt)
        #pragma unroll
        for (int nt = 0; nt < 4; ++nt) {
            const int row0 = rowBase + wm + mt * 16 + quad * 4;
            const int col  = colBase + wn + nt * 16 + lr;
            const float b = BIAS ? bias[col] : 0.f;
            #pragma unroll
            for (int r = 0; r < 4; ++r) {
                const int row = row0 + r;
                float v = acc[mt][nt][r] + b;
                if (RES)     v += resid[(long)row * ldc + col];
                if (OUT_F32) Cf[(long)row * ldc + col] = v;
                else         Cb[(long)row * ldc + col] = f2bf(v);
            }
        }
}

// Fused attention v9: swapped-QK^T, P IN-REGISTER (T12 family).
// sv = mfma(K_frag, Q_frag): lane = q-row (lr), regs = keys (quad*4+r) — the
// SAME fragment reads as r7 (K A-frag = staged sK read; Q B-frag = qa regs),
// only the argument order changes. P never touches LDS: each wave does
// S -> exp -> PV for its own 16 q-rows x 128 cols. No sP, no P-barrier, no
// S-wave/PV-wave role split (r7's stall). V staged in LDS per block (keys
// permuted B-frags read as two b64 chunks: keys 4q..+3 and 16+4q..+3 — bank
// math: 2-way, free). K+V double-buffered, ONE barrier per iter at loop top.
// Geometry: KVBLK=32, 64 iters; block = 4 waves = 64 q-rows x 128 cols;
// grid 1024 (8z x 32qt x 4cs) = 4 blocks/CU; LDS 24.5 KB.
// Lessons kept: sK staging retained (r8: direct-K = latency-bound, -57%).
__global__ __launch_bounds__(256, 4)
void flash_attn(const unsigned short* __restrict__ QK,  // [8*2048][128] (Q|K)
                const unsigned short* __restrict__ VT,  // [8][512][2048]
                unsigned short* __restrict__ O)         // [8*2048][512]
{
    __shared__ __align__(16) unsigned short sK[2][32 * 64];   // 2 x 4 KB  [key][d]
    __shared__ __align__(16) unsigned short sV[2][128 * 32];  // 2 x 8 KB  [col][key]
    __shared__ float sL[64];

    const int bid = blockIdx.x;
    const int z  = bid & 7;          // batch -> XCD (round-robin dispatch)
    const int rr = bid >> 3;
    const int cs = rr & 3;           // 128-col split
    const int qt = rr >> 2;          // Q tile (64 rows), 32 tiles

    const int t = threadIdx.x, w = t >> 6, l = t & 63;
    const int lr = l & 15, quad = l >> 4;

    const long qrow0 = (long)z * 2048 + qt * 64;
    // Q B-frags for this wave's 16 q-rows (rows w*16+lr) — same as r7
    const unsigned short* qp = QK + (qrow0 + w * 16 + lr) * 128 + quad * 8;
    const bf16x8 qa0 = *(const bf16x8*)(qp);
    const bf16x8 qa1 = *(const bf16x8*)(qp + 32);

    // K (byte base): QK[z*2048 + key][64..127], 256 B row stride
    const char* KB = (const char*)QK + (long)z * 2048 * 256 + 128;
    // V (byte base): VT[z][cs*128 + colrow][key], 4096 B col-rows
    const char* VB = (const char*)VT + ((long)z * 512 + cs * 128) * 4096;

    // K staging: 32 key-rows/tile, wave stages 8 (proven pre-swizzle pattern)
    const long kstg = (long)(w * 8 + (l >> 3)) * 256 + (((l & 7) ^ (l >> 3)) << 4);
    // V staging: 128 col-rows of 64 B, wave stages 32 (2 issues x 16 rows;
    // 4 slots/row, swizzle slot ^= (row>>1)&3 == (l>>3)&3 within an issue)
    const long vstg0 = (long)(w * 32 + (l >> 2)) * 4096 + (((l & 3) ^ ((l >> 3) & 3)) << 4);
    const long vstg1 = vstg0 + (long)16 * 4096;

    const int swq = (lr & 7) << 4;        // sK read-side XOR (key&7 == lr&7)
    const int xv  = (lr >> 1) & 3;        // sV read-side swizzle ((colrow>>1)&3)
    // b64 chunk offsets within a 64 B col-row (keys 4q..+3 and 16+4q..+3):
    const int vb1 = ((((quad >> 1)    ) ^ xv) << 4) + ((quad & 1) << 3);
    const int vb2 = ((((quad >> 1) + 2) ^ xv) << 4) + ((quad & 1) << 3);

    f32x4 acc[8];   // [nt]: O rows quad*4+r (of wave's 16), cols cs*128+nt*16+lr
    #pragma unroll
    for (int nt = 0; nt < 8; ++nt) acc[nt] = (f32x4){0.f, 0.f, 0.f, 0.f};
    float lsum = 0.f;   // one q-row (lr) per lane: scalar running sum

    {   // prologue: stage tile 0 into buf 0
        gld_lds16(KB + kstg, (char*)sK[0] + w * 1024);
        gld_lds16(VB + vstg0, (char*)sV[0] + w * 2048);
        gld_lds16(VB + vstg1, (char*)sV[0] + w * 2048 + 1024);
    }

    int cur = 0;
    for (int kt = 0; kt < 64; ++kt) {
        __syncthreads();   // top barrier: prev-iter reads done, staging drained

        if (kt < 63) {     // async-stage NEXT tile into buf^1
            const long kb = (long)(kt + 1) * 8192;   // 32 keys * 256 B
            const long vb = (long)(kt + 1) * 64;     // 32 keys * 2 B
            gld_lds16(KB + kb + kstg, (char*)sK[cur ^ 1] + w * 1024);
            gld_lds16(VB + vb + vstg0, (char*)sV[cur ^ 1] + w * 2048);
            gld_lds16(VB + vb + vstg1, (char*)sV[cur ^ 1] + w * 2048 + 1024);
        }

        // ---- S^T = K Q^T : lane holds P[qrow=lr][keys quad*4+r] per tile ----
        const char* sKc = (const char*)sK[cur];
        unsigned int P[4];   // [L0,H0,L1,H1] = A-frag u32s, keys in canonical order
        #pragma unroll
        for (int nt = 0; nt < 2; ++nt) {
            const int kb = (nt * 16 + lr) * 128;
            bf16x8 k0 = *(const bf16x8*)(sKc + kb + ((quad * 16) ^ swq));
            bf16x8 k1 = *(const bf16x8*)(sKc + kb + ((quad * 16 + 64) ^ swq));
            f32x4 sv = (f32x4){0.f, 0.f, 0.f, 0.f};
            sv = __builtin_amdgcn_mfma_f32_16x16x32_bf16(k0, qa0, sv, 0, 0, 0);
            sv = __builtin_amdgcn_mfma_f32_16x16x32_bf16(k1, qa1, sv, 0, 0, 0);
            const unsigned short b0 = f2bf(__expf(sv[0]));
            const unsigned short b1 = f2bf(__expf(sv[1]));
            const unsigned short b2 = f2bf(__expf(sv[2]));
            const unsigned short b3 = f2bf(__expf(sv[3]));
            lsum += bf2f(b0) + bf2f(b1) + bf2f(b2) + bf2f(b3);
            P[nt * 2]     = (unsigned int)b0 | ((unsigned int)b1 << 16);
            P[nt * 2 + 1] = (unsigned int)b2 | ((unsigned int)b3 << 16);
        }
        union { unsigned int u[4]; bf16x8 v; } pa;
        pa.u[0] = P[0]; pa.u[1] = P[1]; pa.u[2] = P[2]; pa.u[3] = P[3];

        // ---- O += P V : B-frags from sV as b64 pairs (key-permuted order) ----
        const char* sVc = (const char*)sV[cur];
        __builtin_amdgcn_s_setprio(1);
        #pragma unroll
        for (int nt = 0; nt < 8; ++nt) {
            const int crb = (nt * 16 + lr) * 64;
            union { unsigned long long u[2]; bf16x8 v; } vf;
            vf.u[0] = *(const unsigned long long*)(sVc + crb + vb1);
            vf.u[1] = *(const unsigned long long*)(sVc + crb + vb2);
            acc[nt] = __builtin_amdgcn_mfma_f32_16x16x32_bf16(pa.v, vf.v, acc[nt], 0, 0, 0);
        }
        __builtin_amdgcn_s_setprio(0);
        cur ^= 1;
    }

    // ---- lsum: reduce across quads (row lr), redistribute to acc rows ----
    lsum += __shfl_xor(lsum, 16);
    lsum += __shfl_xor(lsum, 32);
    if (l < 16) sL[w * 16 + l] = lsum;    // quad==0 lanes hold row l's full sum
    __syncthreads();

    float inv[4];
    #pragma unroll
    for (int r = 0; r < 4; ++r) inv[r] = 1.0f / sL[w * 16 + quad * 4 + r];
    #pragma unroll
    for (int nt = 0; nt < 8; ++nt) {
        const int col = cs * 128 + nt * 16 + lr;
        #pragma unroll
        for (int r = 0; r < 4; ++r) {
            const long row = qrow0 + w * 16 + quad * 4 + r;
            O[row * 512 + col] = f2bf(acc[nt][r] * inv[r]);
        }
    }
}

extern "C" void kernel_launch(void* const* d_in, const int* in_sizes, int n_in,
                              void* d_out, int out_size, void* d_ws, size_t ws_size,
                              hipStream_t stream)
{
    const float* x  = (const float*)d_in[0];
    const float* wq = (const float*)d_in[1];
    const float* bq = (const float*)d_in[2];
    const float* wk = (const float*)d_in[3];
    const float* bk = (const float*)d_in[4];
    const float* wv = (const float*)d_in[5];
    const float* bv = (const float*)d_in[6];
    const float* wo = (const float*)d_in[7];
    const float* bo = (const float*)d_in[8];

    const int W = 512;
    float* out = (float*)d_out;
    dim3 blk(256);
    char* ws = (char*)d_ws;

    const size_t NEED = 56ull << 20;
    if (ws_size < NEED) return;  // zero-output signature

    unsigned short* QK    = (unsigned short*)(ws);                  //  4 MB [16384 x 128] (Q|K)
    unsigned short* VT    = (unsigned short*)(ws + ( 4ull << 20));  // 16 MB [8][512][2048]
    unsigned short* O     = (unsigned short*)(ws + (20ull << 20));  // 16 MB [16384 x 512]
    unsigned short* xb    = (unsigned short*)(ws + (36ull << 20));  // 16 MB [16384 x 512]
    unsigned short* wAllT = (unsigned short*)(ws + (52ull << 20));  // 640 KB [640][512]
    unsigned short* woT   = (unsigned short*)(ws + (53ull << 20));  // 512 KB [512][512]
    float*          ball  = (float*)         (ws + (53ull << 20) + (512ull << 10)); // 2.5 KB

    // pack: x->bf16, bias concat, weights -> bf16 B^T layouts (merged launch)
    pack<<<dim3(2048 + 256), blk, 0, stream>>>(x, xb, bq, bk, bv, ball,
                                               wv, wo, wq, wk, wAllT, woT);

    // Fused QKV projection: [QK | V] = xb @ [wq|wk|wv] + [bq|bk|bv]
    gemm64<true, false, false, true, 5><<<dim3(1280), blk, 0, stream>>>(
        xb, W, wAllT, W, QK, 128, VT, ball, nullptr, W);

    // Fused attention (no S): O = softmax(Q K^T) V — in-register P, 1024 blocks
    flash_attn<<<dim3(1024), blk, 0, stream>>>(QK, VT, O);

    // out = O @ wo + bo + x  (fp32)
    gemm64<true, true, true, false, 4><<<dim3(1024), blk, 0, stream>>>(
        O, W, woT, W, out, W, nullptr, bo, x, W);
}

// Round 10
// 207.088 us; speedup vs baseline: 1.2438x; 1.0731x over previous
//
#include <hip/hip_runtime.h>

typedef __bf16 bf16x8 __attribute__((ext_vector_type(8)));
typedef float  f32x4  __attribute__((ext_vector_type(4)));

union U8 { uint4 v; unsigned short u[8]; };

static __device__ __forceinline__ float bf2f(unsigned short u) {
    union { unsigned int i; float f; } c; c.i = ((unsigned int)u) << 16; return c.f;
}
static __device__ __forceinline__ unsigned short f2bf(float f) {
    union { float f; unsigned int i; } c; c.f = f;
    unsigned int x = c.i;
    unsigned int r = (x + 0x7FFFu + ((x >> 16) & 1u)) >> 16;  // RNE
    return (unsigned short)r;
}

static __device__ __forceinline__ U8 load8(const float* p) {
    U8 r;
    const float4 a = *(const float4*)p;
    const float4 b = *(const float4*)(p + 4);
    r.u[0] = f2bf(a.x); r.u[1] = f2bf(a.y); r.u[2] = f2bf(a.z); r.u[3] = f2bf(a.w);
    r.u[4] = f2bf(b.x); r.u[5] = f2bf(b.y); r.u[6] = f2bf(b.z); r.u[7] = f2bf(b.w);
    return r;
}

// async global->LDS, 16B per lane. LDS dest must be wave-uniform base (+lane*16 by HW).
static __device__ __forceinline__ void gld_lds16(const void* g, void* l) {
    __builtin_amdgcn_global_load_lds(
        (const __attribute__((address_space(1))) unsigned int*)g,
        (__attribute__((address_space(3))) unsigned int*)l, 16, 0, 0);
}

// ---- merged pack pass: bid<2048: x f32->bf16 + bias concat; else weight transpose ----
// wAllT[640][512] = [wq^T | wk^T | wv^T], woT[512][512], ball[640] = [bq|bk|bv]
__global__ __launch_bounds__(256)
void pack(const float* __restrict__ x, unsigned short* __restrict__ xb,
          const float* __restrict__ bq, const float* __restrict__ bk,
          const float* __restrict__ bv, float* __restrict__ ball,
          const float* __restrict__ wv, const float* __restrict__ wo,
          const float* __restrict__ wq, const float* __restrict__ wk,
          unsigned short* __restrict__ wAllT, unsigned short* __restrict__ woT)
{
    const int bid = blockIdx.x, t = threadIdx.x;
    if (bid < 2048) {
        const long i = ((long)bid * 256 + t) * 16;
        U8 a = load8(x + i);
        U8 b = load8(x + i + 8);
        *(uint4*)(xb + i) = a.v;
        *(uint4*)(xb + i + 8) = b.v;
        if (bid == 0) {
            ball[t]       = t < 64 ? bq[t] : (t < 128 ? bk[t - 64] : bv[t - 128]);
            ball[t + 256] = bv[t + 128];
            if (t < 128) ball[t + 512] = bv[t + 384];
        }
        return;
    }
    // transpose+convert: dst[C][R] = src[R][C]^T, 64x64 tiles
    __shared__ float sT[64][65];
    const int b2 = bid - 2048;
    const int zz = b2 >> 6, rem = b2 & 63;
    const int cx = rem & 7, ry = rem >> 3;
    const float* src; unsigned short* dst; int C;
    if      (zz == 0) { src = wv; dst = wAllT + 128 * 512; C = 512; }
    else if (zz == 1) { src = wo; dst = woT;               C = 512; }
    else if (zz == 2) { src = wq; dst = wAllT;             C = 64;  }
    else              { src = wk; dst = wAllT + 64 * 512;  C = 64;  }
    const int R = 512;
    const int c0 = cx * 64, r0 = ry * 64;
    if (c0 >= C) return;
    #pragma unroll
    for (int k = 0; k < 16; ++k) {
        const int lin = k * 256 + t;
        const int i = lin >> 6, j = lin & 63;
        sT[i][j] = src[(long)(r0 + i) * C + c0 + j];
    }
    __syncthreads();
    #pragma unroll
    for (int k = 0; k < 16; ++k) {
        const int lin = k * 256 + t;
        const int o = lin >> 6, i2 = lin & 63;
        dst[(long)(c0 + o) * R + r0 + i2] = f2bf(sT[i2][o]);
    }
}

// ---- 64x128-tile GEMM, BK=64, DOUBLE-BUFFERED 1-barrier K-loop + XCD swizzle ----
// (r6-measured: -6.5 us vs single-buffered)
template<bool BIAS, bool RES, bool OUT_F32, bool MIXED, int NCOL>
__global__ __launch_bounds__(256, 3)
void gemm64(const unsigned short* __restrict__ A, int lda,
            const unsigned short* __restrict__ B, int ldb,
            void* __restrict__ Cp, int ldc,
            void* __restrict__ Cp2,
            const float* __restrict__ bias,
            const float* __restrict__ resid,
            int K)
{
    __shared__ __align__(16) unsigned short sMem[2][12288];  // 2 x 24 KB (sA 8K | sB 16K)

    const int t = threadIdx.x, wave = t >> 6, lane = t & 63;
    const int lr = lane & 15, quad = lane >> 4;

    // bijective XCD swizzle: nwg = NCOL*256, cpx = NCOL*32 (nwg%8==0)
    const int bid = blockIdx.x;
    const int sw  = (bid & 7) * (NCOL * 32) + (bid >> 3);
    const int rowBase = (sw / NCOL) * 64;
    const int colBase = (sw % NCOL) * 128;
    const int wm = (wave & 1) * 32, wn = (wave >> 1) * 64;

    const int srow  = lane >> 3;
    const int sslot = lane & 7;
    const int swz   = (sslot ^ srow) << 4;   // pre-swizzled source (row&7 == srow)

    f32x4 acc[2][4];
    #pragma unroll
    for (int mt = 0; mt < 2; ++mt)
        #pragma unroll
        for (int nt = 0; nt < 4; ++nt) acc[mt][nt] = (f32x4){0.f, 0.f, 0.f, 0.f};

    auto STAGE = [&](int buf, int kt) {
        unsigned short* sA = sMem[buf];
        unsigned short* sB = sMem[buf] + 4096;
        #pragma unroll
        for (int is = 0; is < 2; ++is) {
            const int r0 = wave * 16 + is * 8;
            gld_lds16((const char*)A + ((long)(rowBase + r0 + srow) * lda + kt) * 2 + swz,
                      (char*)sA + r0 * 128);
        }
        #pragma unroll
        for (int is = 0; is < 4; ++is) {
            const int r0 = wave * 32 + is * 8;
            gld_lds16((const char*)B + ((long)(colBase + r0 + srow) * ldb + kt) * 2 + swz,
                      (char*)sB + r0 * 128);
        }
    };

    STAGE(0, 0);
    __syncthreads();

    int cur = 0;
    for (int kt = 0; kt < K; kt += 64) {
        if (kt + 64 < K) STAGE(cur ^ 1, kt + 64);

        const unsigned short* sA = sMem[cur];
        const unsigned short* sB = sMem[cur] + 4096;
        #pragma unroll
        for (int ks = 0; ks < 2; ++ks) {
            const int kb = ks * 64 + quad * 16;
            bf16x8 bfr[4];
            #pragma unroll
            for (int nt = 0; nt < 4; ++nt) {
                const int row = wn + nt * 16 + lr;
                bfr[nt] = *(const bf16x8*)((const char*)sB + row * 128 + (kb ^ ((row & 7) << 4)));
            }
            #pragma unroll
            for (int mt = 0; mt < 2; ++mt) {
                const int row = wm + mt * 16 + lr;
                bf16x8 af = *(const bf16x8*)((const char*)sA + row * 128 + (kb ^ ((row & 7) << 4)));
                #pragma unroll
                for (int nt = 0; nt < 4; ++nt)
                    acc[mt][nt] = __builtin_amdgcn_mfma_f32_16x16x32_bf16(af, bfr[nt], acc[mt][nt], 0, 0, 0);
            }
        }
        __syncthreads();
        cur ^= 1;
    }

    if (MIXED && colBase >= 128) {
        unsigned short* sT = sMem[0];
        #pragma unroll
        for (int mt = 0; mt < 2; ++mt)
            #pragma unroll
            for (int nt = 0; nt < 4; ++nt) {
                const int row0 = wm + mt * 16 + quad * 4;
                const int col  = wn + nt * 16 + lr;
                const float b = BIAS ? bias[colBase + col] : 0.f;
                ushort4 v4;
                v4.x = f2bf(acc[mt][nt][0] + b);
                v4.y = f2bf(acc[mt][nt][1] + b);
                v4.z = f2bf(acc[mt][nt][2] + b);
                v4.w = f2bf(acc[mt][nt][3] + b);
                *(ushort4*)&sT[col * 72 + row0] = v4;
            }
        __syncthreads();
        unsigned short* C2 = (unsigned short*)Cp2;
        const int bat = rowBase >> 11, key0 = rowBase & 2047;
        const long vcol0 = colBase - 128;
        #pragma unroll
        for (int ro = 0; ro < 4; ++ro) {
            const int flat = ro * 256 + t;
            const int col = flat >> 3, ch = flat & 7;
            const uint4 v = *(const uint4*)&sT[col * 72 + ch * 8];
            *(uint4*)&C2[((long)bat * 512 + vcol0 + col) * 2048 + key0 + ch * 8] = v;
        }
        return;
    }

    float* Cf = (float*)Cp;
    unsigned short* Cb = (unsigned short*)Cp;
    #pragma unroll
    for (int mt = 0; mt < 2; ++mt)
        #pragma unroll
        for (int nt = 0; nt < 4; ++nt) {
            const int row0 = rowBase + wm + mt * 16 + quad * 4;
            const int col  = colBase + wn + nt * 16 + lr;
            const float b = BIAS ? bias[col] : 0.f;
            #pragma unroll
            for (int r = 0; r < 4; ++r) {
                const int row = row0 + r;
                float v = acc[mt][nt][r] + b;
                if (RES)     v += resid[(long)row * ldc + col];
                if (OUT_F32) Cf[(long)row * ldc + col] = v;
                else         Cb[(long)row * ldc + col] = f2bf(v);
            }
        }
}

// Fused attention, 8-WAVE blocks (r7-measured optimum: 83.5 us, total 200.45).
// 64 Q-rows x 256 V-cols, 512 blocks (2 cs x 32 qt x 8 z), 2 blocks/CU.
// Waves 0-3 ("S-waves"): S+exp, 16 rows x 64 keys each (latency hiding intact).
// Waves 4-7 ("stage-waves"): K-tile staging + barrier wait. ALL 8 waves run PV
// on their own 32-col slice, sharing P via sP. Chip-wide S-MFMA/exp/K-traffic
// halved vs 4-wave version. REVERTED here byte-exactly after r8/r9 structural
// experiments (direct-K, sP swizzle, in-register P) all regressed.
__global__ __launch_bounds__(512, 4)
void flash_attn(const unsigned short* __restrict__ QK,  // [8*2048][128] (Q|K)
                const unsigned short* __restrict__ VT,  // [8][512][2048]
                unsigned short* __restrict__ O)         // [8*2048][512]
{
    __shared__ __align__(16) unsigned short sK[2][64 * 64];   // 2 x 8 KB
    __shared__ __align__(16) unsigned short sP[2][64 * 72];   // 2 x 9 KB
    __shared__ float sL[64];

    const int bid = blockIdx.x;
    const int z  = bid & 7;          // batch -> XCD (round-robin dispatch)
    const int rr = bid >> 3;
    const int cs = rr & 1;           // 256-col split
    const int qt = rr >> 1;          // Q tile (64 rows), 32 tiles

    const int t = threadIdx.x, wave = t >> 6, lane = t & 63;
    const int lr = lane & 15, quad = lane >> 4;
    const int sw = wave & 3;         // role index within the 4-wave group
    const bool isS = wave < 4;       // wave-uniform

    const long qrow0 = (long)z * 2048 + qt * 64;
    // Q A-frags: S-waves only (rows sw*16 + lr)
    bf16x8 qa0, qa1;
    if (isS) {
        const unsigned short* qp = QK + (qrow0 + sw * 16 + lr) * 128 + quad * 8;
        qa0 = *(const bf16x8*)(qp);
        qa1 = *(const bf16x8*)(qp + 32);
    }

    // K rows at QK[z*2048+key][64..127]: 256 B row stride
    const char* Kb = (const char*)(QK + (long)z * 2048 * 128 + 64);
    const unsigned short* Vb = VT + (long)z * 512 * 2048
                                  + ((long)cs * 256 + wave * 32) * 2048;

    // staging (stage-waves): wave sw stages keys sw*16..+15; PRE-SWIZZLED source
    const long stg_go = (long)(sw * 16 + (lane >> 3)) * 256
                      + (((lane & 7) ^ (lane >> 3)) << 4);
    const int swq = (lr & 7) << 4;   // read-side XOR, (key&7)==(lr&7)

    f32x4 acc[4][2];   // [mt][nt]: rows mt*16+quad*4+r, cols cs*256+wave*32+nt*16+lr
    #pragma unroll
    for (int mt = 0; mt < 4; ++mt)
        #pragma unroll
        for (int nt = 0; nt < 2; ++nt) acc[mt][nt] = (f32x4){0.f, 0.f, 0.f, 0.f};
    float lsum[4] = {0.f, 0.f, 0.f, 0.f};

    if (!isS) {   // prologue: stage-waves stage K tile 0 into sK[0]
        const char* gk = Kb + stg_go;
        char* lk = (char*)sK[0] + sw * 2048;
        gld_lds16(gk, lk);
        gld_lds16(gk + 2048, lk + 1024);
    }
    __syncthreads();

    int cur = 0;
    for (int kt = 0; kt < 32; ++kt) {
        const int key0 = kt * 64;

        // prefetch V frags for THIS tile (S-waves: hides under S+exp; stage-waves:
        // latency absorbed by their barrier wait)
        bf16x8 vv[2][2];
        #pragma unroll
        for (int nt = 0; nt < 2; ++nt) {
            const unsigned short* vp = Vb + (long)(nt * 16 + lr) * 2048 + key0 + quad * 8;
            vv[nt][0] = *(const bf16x8*)(vp);
            vv[nt][1] = *(const bf16x8*)(vp + 32);
        }

        if (!isS) {
            // stage-waves: async-stage NEXT K tile
            if (kt < 31) {
                const char* gk = Kb + (long)(kt + 1) * 16384 + stg_go;
                char* lk = (char*)sK[cur ^ 1] + sw * 2048;
                gld_lds16(gk, lk);
                gld_lds16(gk + 2048, lk + 1024);
            }
        } else {
            // S-waves: S = Q K^T for rows sw*16..+15 x all 64 keys
            const char* sKc = (const char*)sK[cur];
            __bf16* sPb = (__bf16*)sP[cur];
            #pragma unroll
            for (int nt = 0; nt < 4; ++nt) {
                const int kb = (nt * 16 + lr) * 128;
                bf16x8 k0 = *(const bf16x8*)(sKc + kb + ((quad * 16) ^ swq));
                bf16x8 k1 = *(const bf16x8*)(sKc + kb + ((quad * 16 + 64) ^ swq));
                f32x4 sv = (f32x4){0.f, 0.f, 0.f, 0.f};
                sv = __builtin_amdgcn_mfma_f32_16x16x32_bf16(qa0, k0, sv, 0, 0, 0);
                sv = __builtin_amdgcn_mfma_f32_16x16x32_bf16(qa1, k1, sv, 0, 0, 0);
                #pragma unroll
                for (int r = 0; r < 4; ++r) {
                    const float e = __expf(sv[r]);
                    const __bf16 pb = (__bf16)e;       // v_cvt RNE
                    lsum[r] += (float)pb;
                    sPb[(sw * 16 + quad * 4 + r) * 72 + nt * 16 + lr] = pb;
                }
            }
        }

        __syncthreads();   // publishes sP[cur], drains async sK[cur^1] stages

        // O += P V  (all 8 waves; A-frags of P from LDS, B-frags prefetched)
        const unsigned short* sPc = sP[cur];
        __builtin_amdgcn_s_setprio(1);
        #pragma unroll
        for (int mt = 0; mt < 4; ++mt) {
            const unsigned short* pp = &sPc[(mt * 16 + lr) * 72 + quad * 8];
            bf16x8 p0 = *(const bf16x8*)(pp);
            bf16x8 p1 = *(const bf16x8*)(pp + 32);
            acc[mt][0] = __builtin_amdgcn_mfma_f32_16x16x32_bf16(p0, vv[0][0], acc[mt][0], 0, 0, 0);
            acc[mt][0] = __builtin_amdgcn_mfma_f32_16x16x32_bf16(p1, vv[0][1], acc[mt][0], 0, 0, 0);
            acc[mt][1] = __builtin_amdgcn_mfma_f32_16x16x32_bf16(p0, vv[1][0], acc[mt][1], 0, 0, 0);
            acc[mt][1] = __builtin_amdgcn_mfma_f32_16x16x32_bf16(p1, vv[1][1], acc[mt][1], 0, 0, 0);
        }
        __builtin_amdgcn_s_setprio(0);
        cur ^= 1;
    }

    // row sums (S-waves) -> sL -> all waves, then O = acc / l
    if (isS) {
        #pragma unroll
        for (int r = 0; r < 4; ++r) {
            float v = lsum[r];
            v += __shfl_xor(v, 1); v += __shfl_xor(v, 2);
            v += __shfl_xor(v, 4); v += __shfl_xor(v, 8);
            lsum[r] = v;
        }
        if (lr == 0) {
            #pragma unroll
            for (int r = 0; r < 4; ++r) sL[sw * 16 + quad * 4 + r] = lsum[r];
        }
    }
    __syncthreads();

    #pragma unroll
    for (int mt = 0; mt < 4; ++mt) {
        float inv[4];
        #pragma unroll
        for (int r = 0; r < 4; ++r) inv[r] = 1.0f / sL[mt * 16 + quad * 4 + r];
        #pragma unroll
        for (int nt = 0; nt < 2; ++nt) {
            const int col = cs * 256 + wave * 32 + nt * 16 + lr;
            #pragma unroll
            for (int r = 0; r < 4; ++r) {
                const long row = qrow0 + mt * 16 + quad * 4 + r;
                O[row * 512 + col] = f2bf(acc[mt][nt][r] * inv[r]);
            }
        }
    }
}

extern "C" void kernel_launch(void* const* d_in, const int* in_sizes, int n_in,
                              void* d_out, int out_size, void* d_ws, size_t ws_size,
                              hipStream_t stream)
{
    const float* x  = (const float*)d_in[0];
    const float* wq = (const float*)d_in[1];
    const float* bq = (const float*)d_in[2];
    const float* wk = (const float*)d_in[3];
    const float* bk = (const float*)d_in[4];
    const float* wv = (const float*)d_in[5];
    const float* bv = (const float*)d_in[6];
    const float* wo = (const float*)d_in[7];
    const float* bo = (const float*)d_in[8];

    const int W = 512;
    float* out = (float*)d_out;
    dim3 blk(256);
    char* ws = (char*)d_ws;

    const size_t NEED = 56ull << 20;
    if (ws_size < NEED) return;  // zero-output signature

    unsigned short* QK    = (unsigned short*)(ws);                  //  4 MB [16384 x 128] (Q|K)
    unsigned short* VT    = (unsigned short*)(ws + ( 4ull << 20));  // 16 MB [8][512][2048]
    unsigned short* O     = (unsigned short*)(ws + (20ull << 20));  // 16 MB [16384 x 512]
    unsigned short* xb    = (unsigned short*)(ws + (36ull << 20));  // 16 MB [16384 x 512]
    unsigned short* wAllT = (unsigned short*)(ws + (52ull << 20));  // 640 KB [640][512]
    unsigned short* woT   = (unsigned short*)(ws + (53ull << 20));  // 512 KB [512][512]
    float*          ball  = (float*)         (ws + (53ull << 20) + (512ull << 10)); // 2.5 KB

    // pack: x->bf16, bias concat, weights -> bf16 B^T layouts (merged launch)
    pack<<<dim3(2048 + 256), blk, 0, stream>>>(x, xb, bq, bk, bv, ball,
                                               wv, wo, wq, wk, wAllT, woT);

    // Fused QKV projection: [QK | V] = xb @ [wq|wk|wv] + [bq|bk|bv]
    gemm64<true, false, false, true, 5><<<dim3(1280), blk, 0, stream>>>(
        xb, W, wAllT, W, QK, 128, VT, ball, nullptr, W);

    // Fused attention (no S): O = softmax(Q K^T) V — 8-wave blocks, 512 blocks
    flash_attn<<<dim3(512), dim3(512), 0, stream>>>(QK, VT, O);

    // out = O @ wo + bo + x  (fp32)
    gemm64<true, true, true, false, 4><<<dim3(1024), blk, 0, stream>>>(
        O, W, woT, W, out, W, nullptr, bo, x, W);
}

// Round 11
// 198.564 us; speedup vs baseline: 1.2972x; 1.0429x over previous
//
#include <hip/hip_runtime.h>

typedef __bf16 bf16x8 __attribute__((ext_vector_type(8)));
typedef float  f32x4  __attribute__((ext_vector_type(4)));

union U8 { uint4 v; unsigned short u[8]; };

static __device__ __forceinline__ float bf2f(unsigned short u) {
    union { unsigned int i; float f; } c; c.i = ((unsigned int)u) << 16; return c.f;
}
static __device__ __forceinline__ unsigned short f2bf(float f) {
    union { float f; unsigned int i; } c; c.f = f;
    unsigned int x = c.i;
    unsigned int r = (x + 0x7FFFu + ((x >> 16) & 1u)) >> 16;  // RNE
    return (unsigned short)r;
}

static __device__ __forceinline__ U8 load8(const float* p) {
    U8 r;
    const float4 a = *(const float4*)p;
    const float4 b = *(const float4*)(p + 4);
    r.u[0] = f2bf(a.x); r.u[1] = f2bf(a.y); r.u[2] = f2bf(a.z); r.u[3] = f2bf(a.w);
    r.u[4] = f2bf(b.x); r.u[5] = f2bf(b.y); r.u[6] = f2bf(b.z); r.u[7] = f2bf(b.w);
    return r;
}

// async global->LDS, 16B per lane. LDS dest must be wave-uniform base (+lane*16 by HW).
static __device__ __forceinline__ void gld_lds16(const void* g, void* l) {
    __builtin_amdgcn_global_load_lds(
        (const __attribute__((address_space(1))) unsigned int*)g,
        (__attribute__((address_space(3))) unsigned int*)l, 16, 0, 0);
}

// ---- merged pack pass: bid<2048: x f32->bf16 + bias concat; else weight transpose ----
// wAllT[640][512] = [wq^T | wk^T | wv^T], woT[512][512], ball[640] = [bq|bk|bv]
__global__ __launch_bounds__(256)
void pack(const float* __restrict__ x, unsigned short* __restrict__ xb,
          const float* __restrict__ bq, const float* __restrict__ bk,
          const float* __restrict__ bv, float* __restrict__ ball,
          const float* __restrict__ wv, const float* __restrict__ wo,
          const float* __restrict__ wq, const float* __restrict__ wk,
          unsigned short* __restrict__ wAllT, unsigned short* __restrict__ woT)
{
    const int bid = blockIdx.x, t = threadIdx.x;
    if (bid < 2048) {
        const long i = ((long)bid * 256 + t) * 16;
        U8 a = load8(x + i);
        U8 b = load8(x + i + 8);
        *(uint4*)(xb + i) = a.v;
        *(uint4*)(xb + i + 8) = b.v;
        if (bid == 0) {
            ball[t]       = t < 64 ? bq[t] : (t < 128 ? bk[t - 64] : bv[t - 128]);
            ball[t + 256] = bv[t + 128];
            if (t < 128) ball[t + 512] = bv[t + 384];
        }
        return;
    }
    // transpose+convert: dst[C][R] = src[R][C]^T, 64x64 tiles
    __shared__ float sT[64][65];
    const int b2 = bid - 2048;
    const int zz = b2 >> 6, rem = b2 & 63;
    const int cx = rem & 7, ry = rem >> 3;
    const float* src; unsigned short* dst; int C;
    if      (zz == 0) { src = wv; dst = wAllT + 128 * 512; C = 512; }
    else if (zz == 1) { src = wo; dst = woT;               C = 512; }
    else if (zz == 2) { src = wq; dst = wAllT;             C = 64;  }
    else              { src = wk; dst = wAllT + 64 * 512;  C = 64;  }
    const int R = 512;
    const int c0 = cx * 64, r0 = ry * 64;
    if (c0 >= C) return;
    #pragma unroll
    for (int k = 0; k < 16; ++k) {
        const int lin = k * 256 + t;
        const int i = lin >> 6, j = lin & 63;
        sT[i][j] = src[(long)(r0 + i) * C + c0 + j];
    }
    __syncthreads();
    #pragma unroll
    for (int k = 0; k < 16; ++k) {
        const int lin = k * 256 + t;
        const int o = lin >> 6, i2 = lin & 63;
        dst[(long)(c0 + o) * R + r0 + i2] = f2bf(sT[i2][o]);
    }
}

// ---- 64x128-tile GEMM, BK=64, DOUBLE-BUFFERED 1-barrier K-loop + XCD swizzle ----
// (r6-measured: -6.5 us vs single-buffered; byte-identical r6/r7/r10)
template<bool BIAS, bool RES, bool OUT_F32, bool MIXED, int NCOL>
__global__ __launch_bounds__(256, 3)
void gemm64(const unsigned short* __restrict__ A, int lda,
            const unsigned short* __restrict__ B, int ldb,
            void* __restrict__ Cp, int ldc,
            void* __restrict__ Cp2,
            const float* __restrict__ bias,
            const float* __restrict__ resid,
            int K)
{
    __shared__ __align__(16) unsigned short sMem[2][12288];  // 2 x 24 KB (sA 8K | sB 16K)

    const int t = threadIdx.x, wave = t >> 6, lane = t & 63;
    const int lr = lane & 15, quad = lane >> 4;

    // bijective XCD swizzle: nwg = NCOL*256, cpx = NCOL*32 (nwg%8==0)
    const int bid = blockIdx.x;
    const int sw  = (bid & 7) * (NCOL * 32) + (bid >> 3);
    const int rowBase = (sw / NCOL) * 64;
    const int colBase = (sw % NCOL) * 128;
    const int wm = (wave & 1) * 32, wn = (wave >> 1) * 64;

    const int srow  = lane >> 3;
    const int sslot = lane & 7;
    const int swz   = (sslot ^ srow) << 4;   // pre-swizzled source (row&7 == srow)

    f32x4 acc[2][4];
    #pragma unroll
    for (int mt = 0; mt < 2; ++mt)
        #pragma unroll
        for (int nt = 0; nt < 4; ++nt) acc[mt][nt] = (f32x4){0.f, 0.f, 0.f, 0.f};

    auto STAGE = [&](int buf, int kt) {
        unsigned short* sA = sMem[buf];
        unsigned short* sB = sMem[buf] + 4096;
        #pragma unroll
        for (int is = 0; is < 2; ++is) {
            const int r0 = wave * 16 + is * 8;
            gld_lds16((const char*)A + ((long)(rowBase + r0 + srow) * lda + kt) * 2 + swz,
                      (char*)sA + r0 * 128);
        }
        #pragma unroll
        for (int is = 0; is < 4; ++is) {
            const int r0 = wave * 32 + is * 8;
            gld_lds16((const char*)B + ((long)(colBase + r0 + srow) * ldb + kt) * 2 + swz,
                      (char*)sB + r0 * 128);
        }
    };

    STAGE(0, 0);
    __syncthreads();

    int cur = 0;
    for (int kt = 0; kt < K; kt += 64) {
        if (kt + 64 < K) STAGE(cur ^ 1, kt + 64);

        const unsigned short* sA = sMem[cur];
        const unsigned short* sB = sMem[cur] + 4096;
        #pragma unroll
        for (int ks = 0; ks < 2; ++ks) {
            const int kb = ks * 64 + quad * 16;
            bf16x8 bfr[4];
            #pragma unroll
            for (int nt = 0; nt < 4; ++nt) {
                const int row = wn + nt * 16 + lr;
                bfr[nt] = *(const bf16x8*)((const char*)sB + row * 128 + (kb ^ ((row & 7) << 4)));
            }
            #pragma unroll
            for (int mt = 0; mt < 2; ++mt) {
                const int row = wm + mt * 16 + lr;
                bf16x8 af = *(const bf16x8*)((const char*)sA + row * 128 + (kb ^ ((row & 7) << 4)));
                #pragma unroll
                for (int nt = 0; nt < 4; ++nt)
                    acc[mt][nt] = __builtin_amdgcn_mfma_f32_16x16x32_bf16(af, bfr[nt], acc[mt][nt], 0, 0, 0);
            }
        }
        __syncthreads();
        cur ^= 1;
    }

    if (MIXED && colBase >= 128) {
        unsigned short* sT = sMem[0];
        #pragma unroll
        for (int mt = 0; mt < 2; ++mt)
            #pragma unroll
            for (int nt = 0; nt < 4; ++nt) {
                const int row0 = wm + mt * 16 + quad * 4;
                const int col  = wn + nt * 16 + lr;
                const float b = BIAS ? bias[colBase + col] : 0.f;
                ushort4 v4;
                v4.x = f2bf(acc[mt][nt][0] + b);
                v4.y = f2bf(acc[mt][nt][1] + b);
                v4.z = f2bf(acc[mt][nt][2] + b);
                v4.w = f2bf(acc[mt][nt][3] + b);
                *(ushort4*)&sT[col * 72 + row0] = v4;
            }
        __syncthreads();
        unsigned short* C2 = (unsigned short*)Cp2;
        const int bat = rowBase >> 11, key0 = rowBase & 2047;
        const long vcol0 = colBase - 128;
        #pragma unroll
        for (int ro = 0; ro < 4; ++ro) {
            const int flat = ro * 256 + t;
            const int col = flat >> 3, ch = flat & 7;
            const uint4 v = *(const uint4*)&sT[col * 72 + ch * 8];
            *(uint4*)&C2[((long)bat * 512 + vcol0 + col) * 2048 + key0 + ch * 8] = v;
        }
        return;
    }

    float* Cf = (float*)Cp;
    unsigned short* Cb = (unsigned short*)Cp;
    #pragma unroll
    for (int mt = 0; mt < 2; ++mt)
        #pragma unroll
        for (int nt = 0; nt < 4; ++nt) {
            const int row0 = rowBase + wm + mt * 16 + quad * 4;
            const int col  = colBase + wn + nt * 16 + lr;
            const float b = BIAS ? bias[col] : 0.f;
            #pragma unroll
            for (int r = 0; r < 4; ++r) {
                const int row = row0 + r;
                float v = acc[mt][nt][r] + b;
                if (RES)     v += resid[(long)row * ldc + col];
                if (OUT_F32) Cf[(long)row * ldc + col] = v;
                else         Cb[(long)row * ldc + col] = f2bf(v);
            }
        }
}

// Fused attention, 8-WAVE blocks (r7/r10-measured optimum: 78.5 us).
// SINGLE change this round: sP column XOR-swizzle to kill the 4-way-conflicted
// ds_write_b16 scatter (SQ_LDS_BANK_CONFLICT 4.19M/dispatch, ~8-9% of kernel).
// Element (row,col) lives at col ^ (((row>>3)&1)<<4):
//   write (row = sw*16+quad*4+r): XOR = (quad>>1)<<4 -> the 4 quads write to 4
//     DISJOINT bank octants (16(quad&1) + 8(nt^(quad>>1)) + 4r + lr/2) = free.
//   read  (row = mt*16+lr):       XOR = (lr>>3)<<4  -> b128 lanes still spread
//     8 per 4-bank group (optimal, unchanged); p1 = p0+32 B preserved.
// Everything else byte-identical to r10.
__global__ __launch_bounds__(512, 4)
void flash_attn(const unsigned short* __restrict__ QK,  // [8*2048][128] (Q|K)
                const unsigned short* __restrict__ VT,  // [8][512][2048]
                unsigned short* __restrict__ O)         // [8*2048][512]
{
    __shared__ __align__(16) unsigned short sK[2][64 * 64];   // 2 x 8 KB
    __shared__ __align__(16) unsigned short sP[2][64 * 72];   // 2 x 9 KB
    __shared__ float sL[64];

    const int bid = blockIdx.x;
    const int z  = bid & 7;          // batch -> XCD (round-robin dispatch)
    const int rr = bid >> 3;
    const int cs = rr & 1;           // 256-col split
    const int qt = rr >> 1;          // Q tile (64 rows), 32 tiles

    const int t = threadIdx.x, wave = t >> 6, lane = t & 63;
    const int lr = lane & 15, quad = lane >> 4;
    const int sw = wave & 3;         // role index within the 4-wave group
    const bool isS = wave < 4;       // wave-uniform

    const long qrow0 = (long)z * 2048 + qt * 64;
    // Q A-frags: S-waves only (rows sw*16 + lr)
    bf16x8 qa0, qa1;
    if (isS) {
        const unsigned short* qp = QK + (qrow0 + sw * 16 + lr) * 128 + quad * 8;
        qa0 = *(const bf16x8*)(qp);
        qa1 = *(const bf16x8*)(qp + 32);
    }

    // K rows at QK[z*2048+key][64..127]: 256 B row stride
    const char* Kb = (const char*)(QK + (long)z * 2048 * 128 + 64);
    const unsigned short* Vb = VT + (long)z * 512 * 2048
                                  + ((long)cs * 256 + wave * 32) * 2048;

    // staging (stage-waves): wave sw stages keys sw*16..+15; PRE-SWIZZLED source
    const long stg_go = (long)(sw * 16 + (lane >> 3)) * 256
                      + (((lane & 7) ^ (lane >> 3)) << 4);
    const int swq = (lr & 7) << 4;   // read-side XOR, (key&7)==(lr&7)

    const int pws = (quad >> 1) << 4;   // sP write col XOR ((row>>3)&1 == quad>>1)
    const int prs = (lr >> 3) << 4;     // sP read  col XOR ((row>>3)&1 == lr>>3)

    f32x4 acc[4][2];   // [mt][nt]: rows mt*16+quad*4+r, cols cs*256+wave*32+nt*16+lr
    #pragma unroll
    for (int mt = 0; mt < 4; ++mt)
        #pragma unroll
        for (int nt = 0; nt < 2; ++nt) acc[mt][nt] = (f32x4){0.f, 0.f, 0.f, 0.f};
    float lsum[4] = {0.f, 0.f, 0.f, 0.f};

    if (!isS) {   // prologue: stage-waves stage K tile 0 into sK[0]
        const char* gk = Kb + stg_go;
        char* lk = (char*)sK[0] + sw * 2048;
        gld_lds16(gk, lk);
        gld_lds16(gk + 2048, lk + 1024);
    }
    __syncthreads();

    int cur = 0;
    for (int kt = 0; kt < 32; ++kt) {
        const int key0 = kt * 64;

        // prefetch V frags for THIS tile (S-waves: hides under S+exp; stage-waves:
        // latency absorbed by their barrier wait)
        bf16x8 vv[2][2];
        #pragma unroll
        for (int nt = 0; nt < 2; ++nt) {
            const unsigned short* vp = Vb + (long)(nt * 16 + lr) * 2048 + key0 + quad * 8;
            vv[nt][0] = *(const bf16x8*)(vp);
            vv[nt][1] = *(const bf16x8*)(vp + 32);
        }

        if (!isS) {
            // stage-waves: async-stage NEXT K tile
            if (kt < 31) {
                const char* gk = Kb + (long)(kt + 1) * 16384 + stg_go;
                char* lk = (char*)sK[cur ^ 1] + sw * 2048;
                gld_lds16(gk, lk);
                gld_lds16(gk + 2048, lk + 1024);
            }
        } else {
            // S-waves: S = Q K^T for rows sw*16..+15 x all 64 keys
            const char* sKc = (const char*)sK[cur];
            __bf16* sPb = (__bf16*)sP[cur];
            #pragma unroll
            for (int nt = 0; nt < 4; ++nt) {
                const int kb = (nt * 16 + lr) * 128;
                bf16x8 k0 = *(const bf16x8*)(sKc + kb + ((quad * 16) ^ swq));
                bf16x8 k1 = *(const bf16x8*)(sKc + kb + ((quad * 16 + 64) ^ swq));
                f32x4 sv = (f32x4){0.f, 0.f, 0.f, 0.f};
                sv = __builtin_amdgcn_mfma_f32_16x16x32_bf16(qa0, k0, sv, 0, 0, 0);
                sv = __builtin_amdgcn_mfma_f32_16x16x32_bf16(qa1, k1, sv, 0, 0, 0);
                #pragma unroll
                for (int r = 0; r < 4; ++r) {
                    const float e = __expf(sv[r]);
                    const __bf16 pb = (__bf16)e;       // v_cvt RNE
                    lsum[r] += (float)pb;
                    sPb[(sw * 16 + quad * 4 + r) * 72 + ((nt * 16 + lr) ^ pws)] = pb;
                }
            }
        }

        __syncthreads();   // publishes sP[cur], drains async sK[cur^1] stages

        // O += P V  (all 8 waves; A-frags of P from LDS, B-frags prefetched)
        const unsigned short* sPc = sP[cur];
        __builtin_amdgcn_s_setprio(1);
        #pragma unroll
        for (int mt = 0; mt < 4; ++mt) {
            const unsigned short* pp = &sPc[(mt * 16 + lr) * 72 + ((quad * 8) ^ prs)];
            bf16x8 p0 = *(const bf16x8*)(pp);
            bf16x8 p1 = *(const bf16x8*)(pp + 32);
            acc[mt][0] = __builtin_amdgcn_mfma_f32_16x16x32_bf16(p0, vv[0][0], acc[mt][0], 0, 0, 0);
            acc[mt][0] = __builtin_amdgcn_mfma_f32_16x16x32_bf16(p1, vv[0][1], acc[mt][0], 0, 0, 0);
            acc[mt][1] = __builtin_amdgcn_mfma_f32_16x16x32_bf16(p0, vv[1][0], acc[mt][1], 0, 0, 0);
            acc[mt][1] = __builtin_amdgcn_mfma_f32_16x16x32_bf16(p1, vv[1][1], acc[mt][1], 0, 0, 0);
        }
        __builtin_amdgcn_s_setprio(0);
        cur ^= 1;
    }

    // row sums (S-waves) -> sL -> all waves, then O = acc / l
    if (isS) {
        #pragma unroll
        for (int r = 0; r < 4; ++r) {
            float v = lsum[r];
            v += __shfl_xor(v, 1); v += __shfl_xor(v, 2);
            v += __shfl_xor(v, 4); v += __shfl_xor(v, 8);
            lsum[r] = v;
        }
        if (lr == 0) {
            #pragma unroll
            for (int r = 0; r < 4; ++r) sL[sw * 16 + quad * 4 + r] = lsum[r];
        }
    }
    __syncthreads();

    #pragma unroll
    for (int mt = 0; mt < 4; ++mt) {
        float inv[4];
        #pragma unroll
        for (int r = 0; r < 4; ++r) inv[r] = 1.0f / sL[mt * 16 + quad * 4 + r];
        #pragma unroll
        for (int nt = 0; nt < 2; ++nt) {
            const int col = cs * 256 + wave * 32 + nt * 16 + lr;
            #pragma unroll
            for (int r = 0; r < 4; ++r) {
                const long row = qrow0 + mt * 16 + quad * 4 + r;
                O[row * 512 + col] = f2bf(acc[mt][nt][r] * inv[r]);
            }
        }
    }
}

extern "C" void kernel_launch(void* const* d_in, const int* in_sizes, int n_in,
                              void* d_out, int out_size, void* d_ws, size_t ws_size,
                              hipStream_t stream)
{
    const float* x  = (const float*)d_in[0];
    const float* wq = (const float*)d_in[1];
    const float* bq = (const float*)d_in[2];
    const float* wk = (const float*)d_in[3];
    const float* bk = (const float*)d_in[4];
    const float* wv = (const float*)d_in[5];
    const float* bv = (const float*)d_in[6];
    const float* wo = (const float*)d_in[7];
    const float* bo = (const float*)d_in[8];

    const int W = 512;
    float* out = (float*)d_out;
    dim3 blk(256);
    char* ws = (char*)d_ws;

    const size_t NEED = 56ull << 20;
    if (ws_size < NEED) return;  // zero-output signature

    unsigned short* QK    = (unsigned short*)(ws);                  //  4 MB [16384 x 128] (Q|K)
    unsigned short* VT    = (unsigned short*)(ws + ( 4ull << 20));  // 16 MB [8][512][2048]
    unsigned short* O     = (unsigned short*)(ws + (20ull << 20));  // 16 MB [16384 x 512]
    unsigned short* xb    = (unsigned short*)(ws + (36ull << 20));  // 16 MB [16384 x 512]
    unsigned short* wAllT = (unsigned short*)(ws + (52ull << 20));  // 640 KB [640][512]
    unsigned short* woT   = (unsigned short*)(ws + (53ull << 20));  // 512 KB [512][512]
    float*          ball  = (float*)         (ws + (53ull << 20) + (512ull << 10)); // 2.5 KB

    // pack: x->bf16, bias concat, weights -> bf16 B^T layouts (merged launch)
    pack<<<dim3(2048 + 256), blk, 0, stream>>>(x, xb, bq, bk, bv, ball,
                                               wv, wo, wq, wk, wAllT, woT);

    // Fused QKV projection: [QK | V] = xb @ [wq|wk|wv] + [bq|bk|bv]
    gemm64<true, false, false, true, 5><<<dim3(1280), blk, 0, stream>>>(
        xb, W, wAllT, W, QK, 128, VT, ball, nullptr, W);

    // Fused attention (no S): O = softmax(Q K^T) V — 8-wave blocks, 512 blocks
    flash_attn<<<dim3(512), dim3(512), 0, stream>>>(QK, VT, O);

    // out = O @ wo + bo + x  (fp32)
    gemm64<true, true, true, false, 4><<<dim3(1024), blk, 0, stream>>>(
        O, W, woT, W, out, W, nullptr, bo, x, W);
}